// Round 13
// baseline (1597.043 us; speedup 1.0000x reference)
//
#include <hip/hip_runtime.h>
#include <hip/hip_bf16.h>

#define H 192
#define HH (192*192)
#define NLAYER 13
#define LSTRIDE (2*HH)         // shorts per layer in fragment-ordered weight buffer

typedef unsigned short u16;
typedef unsigned int u32;

typedef __attribute__((ext_vector_type(8))) short short8;
typedef __attribute__((ext_vector_type(4))) float floatx4;

__device__ __forceinline__ u16 f2bf(float f) {
    u32 u = __float_as_uint(f);
    u32 r = (u + 0x7FFFu + ((u >> 16) & 1u)) >> 16;   // RNE
    return (u16)r;
}
__device__ __forceinline__ float bf2f(u16 h) {
    return __uint_as_float(((u32)h) << 16);
}

// ---------------- CSR construction (scan-free) ----------------

__global__ void hist_kernel(const int* __restrict__ dst, int* __restrict__ counts, int E) {
    int e = blockIdx.x * blockDim.x + threadIdx.x;
    if (e < E) atomicAdd(&counts[dst[e]], 1);
}

__global__ void alloc_kernel(const int* __restrict__ counts, int* __restrict__ rbeg,
                             int* __restrict__ rcnt, int* __restrict__ cursor,
                             int* __restrict__ total, int Nv) {
    int v = blockIdx.x * blockDim.x + threadIdx.x;
    if (v >= Nv) return;
    int c = counts[v];
    int base = atomicAdd(total, c);
    rbeg[v] = base;
    rcnt[v] = c;
    cursor[v] = base;
}

__global__ void scatter_kernel(const int* __restrict__ src, const int* __restrict__ dst,
                               const float* __restrict__ w, int* __restrict__ cursor,
                               int2* __restrict__ ce, int E) {
    int e = blockIdx.x * blockDim.x + threadIdx.x;
    if (e < E) {
        int p = atomicAdd(&cursor[dst[e]], 1);
        int2 pk; pk.x = src[e]; pk.y = __float_as_int(w[e]);
        ce[p] = pk;
    }
}

// ---------------- Weight prep: fragment-ordered, chunk-major ----------------
// Wf[l][group][hl][lane][j], group = ks*12 + nt (one 64-k chunk of hi+lo =
// 24 groups * 1024 shorts = 48KB contiguous). lane = quad*16 + col encodes
// B[n=nt*16+col][k=ks*32+quad*8+j].

__global__ void wprep_kernel(const float* __restrict__ W, u16* __restrict__ Wf, int total) {
    int idx = blockIdx.x * blockDim.x + threadIdx.x;
    if (idx >= total) return;
    int l = idx / HH;
    int rem = idx - l * HH;
    int k = rem / H;
    int n = rem - k * H;
    float v = W[idx];
    u16 hi = f2bf(v);
    u16 lo = f2bf(v - bf2f(hi));
    int ks = k >> 5, quad = (k >> 3) & 3, j = k & 7;
    int nt = n >> 4, col = n & 15;
    int lane = quad * 16 + col;
    size_t base = (size_t)l * LSTRIDE + (size_t)(ks * 12 + nt) * 1024 + lane * 8 + j;
    Wf[base] = hi;
    Wf[base + 512] = lo;
}

// ---------------- features fp32 -> bf16 ----------------

__global__ void conv_kernel(const float* __restrict__ in, u16* __restrict__ out, int total4) {
    int idx = blockIdx.x * blockDim.x + threadIdx.x;
    if (idx >= total4) return;
    float4 v = ((const float4*)in)[idx];
    ushort4 p;
    p.x = f2bf(v.x); p.y = f2bf(v.y); p.z = f2bf(v.z); p.w = f2bf(v.w);
    ((ushort4*)out)[idx] = p;
}

// ---------------- common fma helper ----------------

__device__ __forceinline__ void fma8(float* acc, uint4 q, float w) {
    u32 u[4] = {q.x, q.y, q.z, q.w};
    #pragma unroll
    for (int i = 0; i < 4; i++) {
        float lo = __uint_as_float(u[i] << 16);
        float hi = __uint_as_float(u[i] & 0xFFFF0000u);
        acc[2*i]     += w * lo;
        acc[2*i + 1] += w * hi;
    }
}

// ---------------- Sliced SpMM: aggP[slice][v][24] = (adj @ S)[:, slice*24..] --
// 8 column slices of 24 cols; slice = blockIdx&7 -> one slice per XCD under
// round-robin dispatch; per-XCD gather working set = 25000*24*2B = 1.2MB
// (L2-resident). Thread = one vertex-slice: 3 x uint4 per edge (24 cols),
// 2-edge unroll; plane-major 48B output, fully coalesced.

__global__ __launch_bounds__(256) void spmm_slice(
    const u16* __restrict__ S, const int* __restrict__ rbeg, const int* __restrict__ rcnt,
    const int2* __restrict__ ce, u16* __restrict__ aggP, int Nv)
{
    int b = blockIdx.x;
    int slice = b & 7;
    int vb = b >> 3;
    int v = vb * 256 + threadIdx.x;
    if (v >= Nv) return;
    int beg = rbeg[v], cnt = rcnt[v];
    const int2* cep = ce + beg;
    const u16* Sc = S + slice * 24;
    float acc[24] = {};
    int e = 0;
    for (; e + 1 < cnt; e += 2) {
        int2 p0 = cep[e], p1 = cep[e + 1];
        const u16* r0 = Sc + (size_t)p0.x * H;
        const u16* r1 = Sc + (size_t)p1.x * H;
        uint4 a0 = *(const uint4*)(r0);
        uint4 a1 = *(const uint4*)(r0 + 8);
        uint4 a2 = *(const uint4*)(r0 + 16);
        uint4 b0 = *(const uint4*)(r1);
        uint4 b1 = *(const uint4*)(r1 + 8);
        uint4 b2 = *(const uint4*)(r1 + 16);
        float w0 = __int_as_float(p0.y), w1 = __int_as_float(p1.y);
        fma8(acc + 0, a0, w0); fma8(acc + 8, a1, w0); fma8(acc + 16, a2, w0);
        fma8(acc + 0, b0, w1); fma8(acc + 8, b1, w1); fma8(acc + 16, b2, w1);
    }
    if (e < cnt) {
        int2 p0 = cep[e];
        const u16* r0 = Sc + (size_t)p0.x * H;
        uint4 a0 = *(const uint4*)(r0);
        uint4 a1 = *(const uint4*)(r0 + 8);
        uint4 a2 = *(const uint4*)(r0 + 16);
        float w0 = __int_as_float(p0.y);
        fma8(acc + 0, a0, w0); fma8(acc + 8, a1, w0); fma8(acc + 16, a2, w0);
    }
    u16* dst = aggP + ((size_t)slice * Nv + v) * 24;
    #pragma unroll
    for (int i = 0; i < 3; i++) {
        uint4 p;
        p.x = (u32)f2bf(acc[8*i+0]) | ((u32)f2bf(acc[8*i+1]) << 16);
        p.y = (u32)f2bf(acc[8*i+2]) | ((u32)f2bf(acc[8*i+3]) << 16);
        p.z = (u32)f2bf(acc[8*i+4]) | ((u32)f2bf(acc[8*i+5]) << 16);
        p.w = (u32)f2bf(acc[8*i+6]) | ((u32)f2bf(acc[8*i+7]) << 16);
        *(uint4*)(dst + 8 * i) = p;
    }
}

// ---------------- MFMA GEMM: wave = 16 rows x full 192 cols, A from planes ---
// 3 K-chunks of 48KB fragment-ordered weights, linear-copy staged, conflict-
// free ds_read_b128. A-fragments read from aggP 24-wide planes (each 8-wide
// k-window lies in one plane since 8|24: inner in {0,8,16}).
// mode 0: out_bf = bf16(relu(C+b)); mode 1: f=(resid+relu(C+b))*0.5, out_bf;
// mode 2: mode 1 + out_f = f (fp32).

__global__ __launch_bounds__(256) void gemm_fused(
    const u16* __restrict__ aggP, const u16* __restrict__ Wf,
    const float* __restrict__ bias, u16* __restrict__ out_bf, float* __restrict__ out_f,
    const u16* __restrict__ resid_bf, int mode, int M)
{
    __shared__ u16 sh[24576];            // 48KB: one K-chunk
    int tid = threadIdx.x;
    int wave = tid >> 6, lane = tid & 63;
    int col = lane & 15, quad = lane >> 4;
    int rm = (blockIdx.x * 4 + wave) * 16;

    int arow = rm + col;
    if (arow >= M) arow = M - 1;
    short8 a[6];
    #pragma unroll
    for (int ks = 0; ks < 6; ks++) {
        int k0 = ks * 32 + quad * 8;
        int pl = k0 / 24, inner = k0 - pl * 24;
        a[ks] = *(const short8*)(aggP + ((size_t)pl * M + arow) * 24 + inner);
    }

    floatx4 acc[12];
    #pragma unroll
    for (int nt = 0; nt < 12; nt++) acc[nt] = (floatx4){0.f, 0.f, 0.f, 0.f};

    for (int kc = 0; kc < 3; kc++) {
        if (kc) __syncthreads();
        const u16* src = Wf + (size_t)kc * 24576;
        #pragma unroll
        for (int i = 0; i < 12; i++) {
            int idx = tid + i * 256;
            *(uint4*)&sh[idx * 8] = *(const uint4*)(src + (size_t)idx * 8);
        }
        __syncthreads();
        #pragma unroll
        for (int ksl = 0; ksl < 2; ksl++) {
            #pragma unroll
            for (int nt = 0; nt < 12; nt++) {
                int p = (ksl * 12 + nt) * 1024 + lane * 8;
                short8 bh = *(const short8*)&sh[p];
                short8 bl = *(const short8*)&sh[p + 512];
                acc[nt] = __builtin_amdgcn_mfma_f32_16x16x32_bf16(a[kc*2+ksl], bh, acc[nt], 0, 0, 0);
                acc[nt] = __builtin_amdgcn_mfma_f32_16x16x32_bf16(a[kc*2+ksl], bl, acc[nt], 0, 0, 0);
            }
        }
    }

    #pragma unroll
    for (int nt = 0; nt < 12; nt++) {
        int n = nt * 16 + col;
        float b = bias[n];
        #pragma unroll
        for (int r = 0; r < 4; r++) {
            int row = rm + quad * 4 + r;
            if (row < M) {
                float z = fmaxf(acc[nt][r] + b, 0.f);
                size_t o = (size_t)row * H + n;
                if (mode >= 1) {
                    float f = (bf2f(resid_bf[o]) + z) * 0.5f;
                    out_bf[o] = f2bf(f);
                    if (mode == 2) out_f[o] = f;
                } else {
                    out_bf[o] = f2bf(z);
                }
            }
        }
    }
}

// ---------------- Output head: coords = agg @ W_out + b_out (from planes) ----

__global__ void head_kernel(const u16* __restrict__ aggP, const float* __restrict__ W,
                            const float* __restrict__ b, float* __restrict__ coords, int M) {
    int row = blockIdx.x * blockDim.x + threadIdx.x;
    if (row >= M) return;
    float a0 = b[0], a1 = b[1], a2 = b[2];
    #pragma unroll
    for (int pl = 0; pl < 8; pl++) {
        const u16* Ar = aggP + ((size_t)pl * M + row) * 24;
        #pragma unroll
        for (int j = 0; j < 24; j++) {
            float x = bf2f(Ar[j]);
            int k = pl * 24 + j;
            a0 += x * W[k * 3 + 0];
            a1 += x * W[k * 3 + 1];
            a2 += x * W[k * 3 + 2];
        }
    }
    coords[row * 3 + 0] = a0;
    coords[row * 3 + 1] = a1;
    coords[row * 3 + 2] = a2;
}

// ---------------- Launch ----------------

extern "C" void kernel_launch(void* const* d_in, const int* in_sizes, int n_in,
                              void* d_out, int out_size, void* d_ws, size_t ws_size,
                              hipStream_t stream) {
    const float* features = (const float*)d_in[0];
    const int*   edge_src = (const int*)d_in[1];
    const int*   edge_dst = (const int*)d_in[2];
    const float* edge_w   = (const float*)d_in[3];
    const float* Ws       = (const float*)d_in[4];
    const float* bs       = (const float*)d_in[5];
    const float* W_out    = (const float*)d_in[6];
    const float* b_out    = (const float*)d_in[7];

    const int N = in_sizes[0] / H;
    const int E = in_sizes[1];

    float* coords = (float*)d_out;
    float* feats  = coords + (size_t)N * 3;   // fp32 final feats (written at gc13 only)

    char* wptr = (char*)d_ws;
    u16* fbf      = (u16*)wptr;   wptr += (size_t)N * H * sizeof(u16);
    u16* xb       = (u16*)wptr;   wptr += (size_t)N * H * sizeof(u16);
    u16* aggP     = (u16*)wptr;   wptr += (size_t)N * H * sizeof(u16);  // 8 planes x [N][24]
    u16* feats_bf = (u16*)wptr;   wptr += (size_t)N * H * sizeof(u16);
    u16* Wf       = (u16*)wptr;   wptr += (size_t)NLAYER * LSTRIDE * sizeof(u16);
    int* counts   = (int*)wptr;   wptr += (size_t)N * sizeof(int);
    int* total    = (int*)wptr;   wptr += 4;
    int* rbeg     = (int*)wptr;   wptr += (size_t)N * sizeof(int);
    int* rcnt     = (int*)wptr;   wptr += (size_t)N * sizeof(int);
    int* cursor   = (int*)wptr;   wptr += (size_t)N * sizeof(int);
    int2* ce      = (int2*)wptr;  wptr += (size_t)E * sizeof(int2);

    // --- build CSR (dst-indexed, scan-free) ---
    hipMemsetAsync(counts, 0, (size_t)(N + 1) * sizeof(int), stream);  // counts + total
    hist_kernel<<<(E + 255) / 256, 256, 0, stream>>>(edge_dst, counts, E);
    alloc_kernel<<<(N + 255) / 256, 256, 0, stream>>>(counts, rbeg, rcnt, cursor, total, N);
    scatter_kernel<<<(E + 255) / 256, 256, 0, stream>>>(edge_src, edge_dst, edge_w,
                                                        cursor, ce, E);

    // --- weight split + fragment reorder + feature conversion ---
    int wtotal = NLAYER * HH;
    wprep_kernel<<<(wtotal + 255) / 256, 256, 0, stream>>>(Ws, Wf, wtotal);
    int c4 = N * H / 4;
    conv_kernel<<<(c4 + 255) / 256, 256, 0, stream>>>(features, fbf, c4);

    int VB = (N + 255) / 256;            // blocks per slice
    int sgrid = 8 * VB;                  // slice = b&7, vb = b>>3
    int mwaves = (N + 15) / 16;
    int gblocks = (mwaves + 3) / 4;

    // L0: x0 = relu((adj@f) W0 + b0)
    spmm_slice<<<sgrid, 256, 0, stream>>>(fbf, rbeg, rcnt, ce, aggP, N);
    gemm_fused<<<gblocks, 256, 0, stream>>>(aggP, Wf + 0 * (size_t)LSTRIDE, bs + 0 * H,
                                            xb, nullptr, nullptr, 0, N);
    // L1: feats = (f + relu((adj@x0) W1 + b1))/2
    spmm_slice<<<sgrid, 256, 0, stream>>>(xb, rbeg, rcnt, ce, aggP, N);
    gemm_fused<<<gblocks, 256, 0, stream>>>(aggP, Wf + 1 * (size_t)LSTRIDE, bs + 1 * H,
                                            feats_bf, nullptr, fbf, 1, N);
    // blocks 2-6
    for (int i = 2; i < 12; i += 2) {
        spmm_slice<<<sgrid, 256, 0, stream>>>(feats_bf, rbeg, rcnt, ce, aggP, N);
        gemm_fused<<<gblocks, 256, 0, stream>>>(aggP, Wf + (size_t)i * LSTRIDE, bs + (size_t)i * H,
                                                xb, nullptr, nullptr, 0, N);
        spmm_slice<<<sgrid, 256, 0, stream>>>(xb, rbeg, rcnt, ce, aggP, N);
        gemm_fused<<<gblocks, 256, 0, stream>>>(aggP, Wf + (size_t)(i+1) * LSTRIDE, bs + (size_t)(i+1) * H,
                                                feats_bf, nullptr, feats_bf, 1, N);
    }
    // gc13: also writes fp32 feats to d_out
    spmm_slice<<<sgrid, 256, 0, stream>>>(feats_bf, rbeg, rcnt, ce, aggP, N);
    gemm_fused<<<gblocks, 256, 0, stream>>>(aggP, Wf + 12 * (size_t)LSTRIDE, bs + 12 * H,
                                            feats_bf, feats, feats_bf, 2, N);

    // head: coords = (adj@feats) W_out + b_out
    spmm_slice<<<sgrid, 256, 0, stream>>>(feats_bf, rbeg, rcnt, ce, aggP, N);
    head_kernel<<<(N + 255) / 256, 256, 0, stream>>>(aggP, W_out, b_out, coords, N);
}

// Round 16
// 623.965 us; speedup vs baseline: 2.5595x; 2.5595x over previous
//
#include <hip/hip_runtime.h>
#include <hip/hip_bf16.h>

#define H 192
#define HH (192*192)
#define NLAYER 13
#define LSTRIDE (2*HH)         // shorts per layer in fragment-ordered weight buffer
#define ASTRIDE 200            // A-tile row stride in shorts (400B, 16B-aligned)

typedef unsigned short u16;
typedef unsigned int u32;

typedef __attribute__((ext_vector_type(8))) short short8;
typedef __attribute__((ext_vector_type(4))) float floatx4;

__device__ __forceinline__ u16 f2bf(float f) {
    u32 u = __float_as_uint(f);
    u32 r = (u + 0x7FFFu + ((u >> 16) & 1u)) >> 16;   // RNE
    return (u16)r;
}
__device__ __forceinline__ float bf2f(u16 h) {
    return __uint_as_float(((u32)h) << 16);
}

// ---------------- CSR construction (scan-free) ----------------

__global__ void hist_kernel(const int* __restrict__ dst, int* __restrict__ counts, int E) {
    int e = blockIdx.x * blockDim.x + threadIdx.x;
    if (e < E) atomicAdd(&counts[dst[e]], 1);
}

__global__ void alloc_kernel(const int* __restrict__ counts, int* __restrict__ rbeg,
                             int* __restrict__ rcnt, int* __restrict__ cursor,
                             int* __restrict__ total, int Nv) {
    int v = blockIdx.x * blockDim.x + threadIdx.x;
    if (v >= Nv) return;
    int c = counts[v];
    int base = atomicAdd(total, c);
    rbeg[v] = base;
    rcnt[v] = c;
    cursor[v] = base;
}

__global__ void scatter_kernel(const int* __restrict__ src, const int* __restrict__ dst,
                               const float* __restrict__ w, int* __restrict__ cursor,
                               int2* __restrict__ ce, int E) {
    int e = blockIdx.x * blockDim.x + threadIdx.x;
    if (e < E) {
        int p = atomicAdd(&cursor[dst[e]], 1);
        int2 pk; pk.x = src[e]; pk.y = __float_as_int(w[e]);
        ce[p] = pk;
    }
}

// ---------------- Weight prep: fragment-ordered ----------------
// Wf[l][group][hl][lane][j], group = ks*12 + nt. lane = quad*16 + col encodes
// B[n=nt*16+col][k=ks*32+quad*8+j]; hi at +0, lo at +512 within the group.

__global__ void wprep_kernel(const float* __restrict__ W, u16* __restrict__ Wf, int total) {
    int idx = blockIdx.x * blockDim.x + threadIdx.x;
    if (idx >= total) return;
    int l = idx / HH;
    int rem = idx - l * HH;
    int k = rem / H;
    int n = rem - k * H;
    float v = W[idx];
    u16 hi = f2bf(v);
    u16 lo = f2bf(v - bf2f(hi));
    int ks = k >> 5, quad = (k >> 3) & 3, j = k & 7;
    int nt = n >> 4, col = n & 15;
    int lane = quad * 16 + col;
    size_t base = (size_t)l * LSTRIDE + (size_t)(ks * 12 + nt) * 1024 + lane * 8 + j;
    Wf[base] = hi;
    Wf[base + 512] = lo;
}

// ---------------- features fp32 -> bf16 ----------------

__global__ void conv_kernel(const float* __restrict__ in, u16* __restrict__ out, int total4) {
    int idx = blockIdx.x * blockDim.x + threadIdx.x;
    if (idx >= total4) return;
    float4 v = ((const float4*)in)[idx];
    ushort4 p;
    p.x = f2bf(v.x); p.y = f2bf(v.y); p.z = f2bf(v.z); p.w = f2bf(v.w);
    ((ushort4*)out)[idx] = p;
}

// ---------------- common fma helper ----------------

__device__ __forceinline__ void fma8(float* acc, uint4 q, float w) {
    u32 u[4] = {q.x, q.y, q.z, q.w};
    #pragma unroll
    for (int i = 0; i < 4; i++) {
        float lo = __uint_as_float(u[i] << 16);
        float hi = __uint_as_float(u[i] & 0xFFFF0000u);
        acc[2*i]     += w * lo;
        acc[2*i + 1] += w * hi;
    }
}

// ---------------- Fused layer: agg = adj @ S ; out = epilogue(agg @ W + b) ---
// RACE RULE: S (gather input) must NEVER alias out_bf/out_f — late blocks
// gather rows early blocks already wrote. resid_bf may alias S (read-only).
// Block = 384 threads = 16 dst vertices x 24 lanes.
// Phase 1: lane owns 8 cols, one uint4/edge, 4-edge unroll -> LDS A-tile.
// Phase 2: 6 waves; wave w does n-tiles {w, w+6}; B-frags direct from
//   fragment-ordered Wf (lane-contiguous 16B, L2-hot); A via ds_read_b128.
// mode 0: out_bf = bf16(relu(C+b)); mode 1: f=(resid+relu(C+b))*0.5 -> out_bf;
// mode 2: mode 1 + out_f = f (fp32).

__global__ __launch_bounds__(384) void fused_layer(
    const u16* __restrict__ S, const int* __restrict__ rbeg, const int* __restrict__ rcnt,
    const int2* __restrict__ ce, const u16* __restrict__ Wf, const float* __restrict__ bias,
    u16* __restrict__ out_bf, float* __restrict__ out_f, const u16* __restrict__ resid_bf,
    int mode, int M)
{
    __shared__ u16 shA[16 * ASTRIDE];    // 6.4 KB A-tile
    int tid = threadIdx.x;
    int vg = tid / 24;                   // vertex 0..15
    int l  = tid - vg * 24;              // lane in vertex, owns cols l*8..l*8+7
    int v = blockIdx.x * 16 + vg;

    float acc1[8] = {};
    if (v < M) {
        int beg = rbeg[v], cnt = rcnt[v];
        const int2* cep = ce + beg;
        const u16* Sc = S + l * 8;
        int e = 0;
        for (; e + 3 < cnt; e += 4) {
            int2 p0 = cep[e], p1 = cep[e + 1], p2 = cep[e + 2], p3 = cep[e + 3];
            uint4 q0 = *(const uint4*)(Sc + (size_t)p0.x * H);
            uint4 q1 = *(const uint4*)(Sc + (size_t)p1.x * H);
            uint4 q2 = *(const uint4*)(Sc + (size_t)p2.x * H);
            uint4 q3 = *(const uint4*)(Sc + (size_t)p3.x * H);
            fma8(acc1, q0, __int_as_float(p0.y));
            fma8(acc1, q1, __int_as_float(p1.y));
            fma8(acc1, q2, __int_as_float(p2.y));
            fma8(acc1, q3, __int_as_float(p3.y));
        }
        for (; e < cnt; e++) {
            int2 p0 = cep[e];
            uint4 q0 = *(const uint4*)(Sc + (size_t)p0.x * H);
            fma8(acc1, q0, __int_as_float(p0.y));
        }
    }
    {
        uint4 p;
        p.x = (u32)f2bf(acc1[0]) | ((u32)f2bf(acc1[1]) << 16);
        p.y = (u32)f2bf(acc1[2]) | ((u32)f2bf(acc1[3]) << 16);
        p.z = (u32)f2bf(acc1[4]) | ((u32)f2bf(acc1[5]) << 16);
        p.w = (u32)f2bf(acc1[6]) | ((u32)f2bf(acc1[7]) << 16);
        *(uint4*)&shA[vg * ASTRIDE + l * 8] = p;
    }
    __syncthreads();

    // ---- phase 2: MFMA (6 waves x 2 n-tiles) ----
    int wave = tid >> 6, lane = tid & 63;
    int col = lane & 15, quad = lane >> 4;

    short8 a[6];
    {
        const u16* Ar = &shA[col * ASTRIDE + quad * 8];
        #pragma unroll
        for (int ks = 0; ks < 6; ks++) a[ks] = *(const short8*)(Ar + ks * 32);
    }

    int nt0 = wave, nt1 = wave + 6;
    floatx4 c0 = {0.f, 0.f, 0.f, 0.f}, c1 = {0.f, 0.f, 0.f, 0.f};
    #pragma unroll
    for (int ks = 0; ks < 6; ks++) {
        const u16* g0 = Wf + (size_t)(ks * 12 + nt0) * 1024 + lane * 8;
        const u16* g1 = Wf + (size_t)(ks * 12 + nt1) * 1024 + lane * 8;
        short8 bh0 = *(const short8*)g0;
        short8 bl0 = *(const short8*)(g0 + 512);
        short8 bh1 = *(const short8*)g1;
        short8 bl1 = *(const short8*)(g1 + 512);
        c0 = __builtin_amdgcn_mfma_f32_16x16x32_bf16(a[ks], bh0, c0, 0, 0, 0);
        c0 = __builtin_amdgcn_mfma_f32_16x16x32_bf16(a[ks], bl0, c0, 0, 0, 0);
        c1 = __builtin_amdgcn_mfma_f32_16x16x32_bf16(a[ks], bh1, c1, 0, 0, 0);
        c1 = __builtin_amdgcn_mfma_f32_16x16x32_bf16(a[ks], bl1, c1, 0, 0, 0);
    }

    // ---- epilogue: C layout col=lane&15, row=quad*4+r ----
    int rm = blockIdx.x * 16;
    #pragma unroll
    for (int half = 0; half < 2; half++) {
        int nt = half ? nt1 : nt0;
        floatx4 cc = half ? c1 : c0;
        int n = nt * 16 + col;
        float b = bias[n];
        #pragma unroll
        for (int r = 0; r < 4; r++) {
            int row = rm + quad * 4 + r;
            if (row < M) {
                float z = fmaxf(cc[r] + b, 0.f);
                size_t o = (size_t)row * H + n;
                if (mode >= 1) {
                    float f = (bf2f(resid_bf[o]) + z) * 0.5f;
                    out_bf[o] = f2bf(f);
                    if (mode == 2) out_f[o] = f;
                } else {
                    out_bf[o] = f2bf(z);
                }
            }
        }
    }
}

// ---------------- head gather: sup = adj @ feats_bf ----------------

__global__ __launch_bounds__(192) void spmm_raw(
    const u16* __restrict__ S, const int* __restrict__ rbeg, const int* __restrict__ rcnt,
    const int2* __restrict__ ce, u16* __restrict__ out, int Nv)
{
    int tid = threadIdx.x;
    int g = tid / 24;
    int l = tid - g * 24;
    int v = blockIdx.x * 8 + g;
    if (v >= Nv) return;
    int beg = rbeg[v], cnt = rcnt[v];
    const int2* cep = ce + beg;
    const u16* Sc = S + l * 8;
    float acc[8] = {};
    int e = 0;
    for (; e + 3 < cnt; e += 4) {
        int2 p0 = cep[e], p1 = cep[e + 1], p2 = cep[e + 2], p3 = cep[e + 3];
        uint4 q0 = *(const uint4*)(Sc + (size_t)p0.x * H);
        uint4 q1 = *(const uint4*)(Sc + (size_t)p1.x * H);
        uint4 q2 = *(const uint4*)(Sc + (size_t)p2.x * H);
        uint4 q3 = *(const uint4*)(Sc + (size_t)p3.x * H);
        fma8(acc, q0, __int_as_float(p0.y));
        fma8(acc, q1, __int_as_float(p1.y));
        fma8(acc, q2, __int_as_float(p2.y));
        fma8(acc, q3, __int_as_float(p3.y));
    }
    for (; e < cnt; e++) {
        int2 p0 = cep[e];
        uint4 q0 = *(const uint4*)(Sc + (size_t)p0.x * H);
        fma8(acc, q0, __int_as_float(p0.y));
    }
    size_t idx = (size_t)v * H + l * 8;
    ushort4 o0, o1;
    o0.x = f2bf(acc[0]); o0.y = f2bf(acc[1]); o0.z = f2bf(acc[2]); o0.w = f2bf(acc[3]);
    o1.x = f2bf(acc[4]); o1.y = f2bf(acc[5]); o1.z = f2bf(acc[6]); o1.w = f2bf(acc[7]);
    *(ushort4*)&out[idx] = o0;
    *(ushort4*)&out[idx + 4] = o1;
}

// ---------------- Output head: coords = sup @ W_out + b_out ----------------

__global__ void head_kernel(const u16* __restrict__ A, const float* __restrict__ W,
                            const float* __restrict__ b, float* __restrict__ coords, int M) {
    int row = blockIdx.x * blockDim.x + threadIdx.x;
    if (row >= M) return;
    float a0 = b[0], a1 = b[1], a2 = b[2];
    const u16* Ar = A + (size_t)row * H;
    for (int k = 0; k < H; k++) {
        float x = bf2f(Ar[k]);
        a0 += x * W[k * 3 + 0];
        a1 += x * W[k * 3 + 1];
        a2 += x * W[k * 3 + 2];
    }
    coords[row * 3 + 0] = a0;
    coords[row * 3 + 1] = a1;
    coords[row * 3 + 2] = a2;
}

// ---------------- Launch ----------------

extern "C" void kernel_launch(void* const* d_in, const int* in_sizes, int n_in,
                              void* d_out, int out_size, void* d_ws, size_t ws_size,
                              hipStream_t stream) {
    const float* features = (const float*)d_in[0];
    const int*   edge_src = (const int*)d_in[1];
    const int*   edge_dst = (const int*)d_in[2];
    const float* edge_w   = (const float*)d_in[3];
    const float* Ws       = (const float*)d_in[4];
    const float* bs       = (const float*)d_in[5];
    const float* W_out    = (const float*)d_in[6];
    const float* b_out    = (const float*)d_in[7];

    const int N = in_sizes[0] / H;
    const int E = in_sizes[1];

    float* coords = (float*)d_out;
    float* feats  = coords + (size_t)N * 3;   // fp32 final feats (written at gc13 only)

    char* wptr = (char*)d_ws;
    u16* fbf  = (u16*)wptr;   wptr += (size_t)N * H * sizeof(u16);  // bf16 features
    u16* xb   = (u16*)wptr;   wptr += (size_t)N * H * sizeof(u16);  // x buffer
    u16* fA   = (u16*)wptr;   wptr += (size_t)N * H * sizeof(u16);  // feats ping
    u16* fB   = (u16*)wptr;   wptr += (size_t)N * H * sizeof(u16);  // feats pong
    u16* sup  = (u16*)wptr;   wptr += (size_t)N * H * sizeof(u16);  // head agg
    u16* Wf   = (u16*)wptr;   wptr += (size_t)NLAYER * LSTRIDE * sizeof(u16);
    int* counts = (int*)wptr; wptr += (size_t)N * sizeof(int);
    int* total  = (int*)wptr; wptr += 4;
    int* rbeg   = (int*)wptr; wptr += (size_t)N * sizeof(int);
    int* rcnt   = (int*)wptr; wptr += (size_t)N * sizeof(int);
    int* cursor = (int*)wptr; wptr += (size_t)N * sizeof(int);
    int2* ce    = (int2*)wptr; wptr += (size_t)E * sizeof(int2);

    // --- build CSR (dst-indexed, scan-free) ---
    hipMemsetAsync(counts, 0, (size_t)(N + 1) * sizeof(int), stream);  // counts + total
    hist_kernel<<<(E + 255) / 256, 256, 0, stream>>>(edge_dst, counts, E);
    alloc_kernel<<<(N + 255) / 256, 256, 0, stream>>>(counts, rbeg, rcnt, cursor, total, N);
    scatter_kernel<<<(E + 255) / 256, 256, 0, stream>>>(edge_src, edge_dst, edge_w,
                                                        cursor, ce, E);

    // --- weight split + fragment reorder + feature conversion ---
    int wtotal = NLAYER * HH;
    wprep_kernel<<<(wtotal + 255) / 256, 256, 0, stream>>>(Ws, Wf, wtotal);
    int c4 = N * H / 4;
    conv_kernel<<<(c4 + 255) / 256, 256, 0, stream>>>(features, fbf, c4);

    int lb = (N + 15) / 16;              // fused-layer blocks
    int VC = (N + 7) / 8;

    // L0: x0 = relu((adj@fbf) W0 + b0)            [gather fbf -> write xb]
    fused_layer<<<lb, 384, 0, stream>>>(fbf, rbeg, rcnt, ce, Wf + 0 * (size_t)LSTRIDE,
                                        bs + 0 * H, xb, nullptr, nullptr, 0, N);
    // L1: fA = (fbf + relu((adj@xb) W1 + b1))/2   [gather xb -> write fA, resid fbf RO]
    fused_layer<<<lb, 384, 0, stream>>>(xb, rbeg, rcnt, ce, Wf + 1 * (size_t)LSTRIDE,
                                        bs + 1 * H, fA, nullptr, fbf, 1, N);

    // blocks 2-6: ping-pong cur/nxt so gather input never aliases output
    u16* cur = fA;
    u16* nxt = fB;
    for (int i = 2; i < 12; i += 2) {
        fused_layer<<<lb, 384, 0, stream>>>(cur, rbeg, rcnt, ce, Wf + (size_t)i * LSTRIDE,
                                            bs + (size_t)i * H, xb, nullptr, nullptr, 0, N);
        fused_layer<<<lb, 384, 0, stream>>>(xb, rbeg, rcnt, ce, Wf + (size_t)(i+1) * LSTRIDE,
                                            bs + (size_t)(i+1) * H, nxt, nullptr, cur, 1, N);
        u16* t = cur; cur = nxt; nxt = t;
    }

    // gc13: gather cur -> write nxt (+ fp32 feats to d_out); resid cur RO
    fused_layer<<<lb, 384, 0, stream>>>(cur, rbeg, rcnt, ce, Wf + 12 * (size_t)LSTRIDE,
                                        bs + 12 * H, nxt, feats, cur, 2, N);

    // head: coords = (adj@nxt) W_out + b_out
    spmm_raw<<<VC, 192, 0, stream>>>(nxt, rbeg, rcnt, ce, sup, N);
    head_kernel<<<(N + 255) / 256, 256, 0, stream>>>(sup, W_out, b_out, coords, N);
}